// Round 1
// baseline (181.310 us; speedup 1.0000x reference)
//
#include <hip/hip_runtime.h>

// Attention_11940009083141 — MI355X, round 11.
// B=2, S=2048, HID=1024, NH=16, HD=64. FP32 in/out; bf16 MFMA internally.
//
// r10 post-mortem: flash BM=256 (4 waves x 64 q-rows) sits at MfmaUtil 27 /
// VALUBusy 32 / Occupancy 17.8 — latency-bound at 2 waves/SIMD (grid 512
// blocks x 4 waves = exactly 2 blocks/CU). VALU diet (r9) was flat -> stalls
// are dependency/barrier latency, not pipe pressure.
//
// Round-11:
//  * flash: 8 waves/block (512 thr), 32 q-rows/wave, BM=256 kept, z=2 kept.
//    Same grid (8,32,2)=512 blocks -> 2 blocks/CU but 16 waves/CU = 4
//    waves/SIMD (2x latency hiding). HBM traffic, MFMA/staged-byte, combine
//    all unchanged. LDS 48KB (pl x8 waves), launch_bounds(512,4), VGPR<=128.
//  * everything else identical to r10.
//
// ws (32MB): q[0,8M) k[8,16M) vT[16,24M) attn[24,32M); Wob over dead q.
// d_out scratch: pre-qkv Wqb@0 Wkb@2M Wvb@4M xb@6M; post-qkv O1@0, L0/L1@8M.

typedef unsigned short u16;
typedef __bf16 bf16x8 __attribute__((ext_vector_type(8)));
typedef float  f32x4  __attribute__((ext_vector_type(4)));
typedef u16    u16x8  __attribute__((ext_vector_type(8)));
typedef u16    u16x4  __attribute__((ext_vector_type(4)));

#define HID 1024
#define SEQ 2048
#define NH  16
#define HD  64

#if __has_builtin(__builtin_amdgcn_exp2f)
#define EXP2F(x) __builtin_amdgcn_exp2f(x)
#else
#define EXP2F(x) exp2f(x)
#endif

__device__ __forceinline__ float bf2f(u16 u) { return __uint_as_float(((unsigned)u) << 16); }
// f32 -> bf16 RNE via native cast
__device__ __forceinline__ u16 f2bf(float f) {
  union { __bf16 h; u16 u; } c;
  c.h = (__bf16)f;
  return c.u;
}
__device__ __forceinline__ void gl_lds16(const void* g, void* l) {
  __builtin_amdgcn_global_load_lds((const __attribute__((address_space(1))) void*)g,
                                   (__attribute__((address_space(3))) void*)l, 16, 0, 0);
}
__device__ __forceinline__ void stage_f32(const float* __restrict__ src, u16* dst) {
  float4 f0 = *(const float4*)src;
  float4 f1 = *(const float4*)(src + 4);
  u16x8 o;
  o[0] = f2bf(f0.x); o[1] = f2bf(f0.y); o[2] = f2bf(f0.z); o[3] = f2bf(f0.w);
  o[4] = f2bf(f1.x); o[5] = f2bf(f1.y); o[6] = f2bf(f1.z); o[7] = f2bf(f1.w);
  *(u16x8*)dst = o;
}
// XOR chunk swizzle: logical 8-u16 chunk c of row r lives at physical chunk c^(r&7)
__device__ __forceinline__ int swz(int c, int r) { return c ^ (r & 7); }

// ---------------- fp32 -> bf16 converts ------------------------------------------------
__global__ void cvt_pre(const float* __restrict__ x,  const float* __restrict__ Wq,
                        const float* __restrict__ Wk, const float* __restrict__ Wv,
                        u16* __restrict__ xb, u16* __restrict__ Wqb,
                        u16* __restrict__ Wkb, u16* __restrict__ Wvb) {
  const int z = blockIdx.y;
  const float* src; u16* dst; int nchunk;
  switch (z) {
    case 0:  src = x;  dst = xb;  nchunk = 524288; break;
    case 1:  src = Wq; dst = Wqb; nchunk = 131072; break;
    case 2:  src = Wk; dst = Wkb; nchunk = 131072; break;
    default: src = Wv; dst = Wvb; nchunk = 131072; break;
  }
  const int i = blockIdx.x * 256 + threadIdx.x;
  if (i >= nchunk) return;
  stage_f32(src + (size_t)i * 8, dst + (size_t)i * 8);
}
__global__ void cvt_wo(const float* __restrict__ Wo, u16* __restrict__ Wob) {
  const int i = blockIdx.x * 256 + threadIdx.x;   // 131072 chunks
  stage_f32(Wo + (size_t)i * 8, Wob + (size_t)i * 8);
}

// ---------------- NT GEMM mainloop: 128x128 tile, BK=64, K=1024, two-sided DMA --------
__device__ __forceinline__ void gemm_mainloop(const u16* __restrict__ Aptr,
                                              const u16* __restrict__ Bptr,
                                              u16* a_lds, u16* b_lds,
                                              int m0, int n0, f32x4 (&acc)[4][4]) {
  const int tid  = threadIdx.x;
  const int w    = tid >> 6;
  const int lane = tid & 63;
  const int quad = lane >> 4, l15 = lane & 15;
  const int wm = (w >> 1) * 64, wn = (w & 1) * 64;
  const int srow = lane >> 3, sc = lane & 7;        // DMA roles: 8 rows x 8 chunks

  for (int k0 = 0; k0 < HID; k0 += 64) {
#pragma unroll
    for (int i = 0; i < 4; ++i) {
      const int seg = w * 4 + i;                    // 16 segs of 8 rows per 128x64 tile
      const int r   = seg * 8 + srow;
      const int col = k0 + swz(sc, srow) * 8;       // swizzled source column
      gl_lds16(Aptr + (size_t)(m0 + r) * HID + col, a_lds + seg * 512);
      gl_lds16(Bptr + (size_t)(n0 + r) * HID + col, b_lds + seg * 512);
    }
    __syncthreads();
#pragma unroll
    for (int kf = 0; kf < 2; ++kf) {
      bf16x8 af[4], bfr[4];
#pragma unroll
      for (int mt = 0; mt < 4; ++mt)
        af[mt] = *(const bf16x8*)&a_lds[(wm + mt * 16 + l15) * 64 + swz(kf * 4 + quad, l15) * 8];
#pragma unroll
      for (int nt = 0; nt < 4; ++nt)
        bfr[nt] = *(const bf16x8*)&b_lds[(wn + nt * 16 + l15) * 64 + swz(kf * 4 + quad, l15) * 8];
#pragma unroll
      for (int mt = 0; mt < 4; ++mt)
#pragma unroll
        for (int nt = 0; nt < 4; ++nt)
          acc[mt][nt] = __builtin_amdgcn_mfma_f32_16x16x32_bf16(af[mt], bfr[nt], acc[mt][nt], 0, 0, 0);
    }
    __syncthreads();
  }
}

// ---------------- NT GEMM mainloop: 64x128 tile (out_gemm) -----------------------------
__device__ __forceinline__ void gemm64_mainloop(const u16* __restrict__ Aptr,
                                                const u16* __restrict__ Bptr,
                                                u16* a_lds, u16* b_lds,
                                                int m0, int n0, f32x4 (&acc)[2][4]) {
  const int tid  = threadIdx.x;
  const int w    = tid >> 6;
  const int lane = tid & 63;
  const int quad = lane >> 4, l15 = lane & 15;
  const int wm = (w >> 1) * 32, wn = (w & 1) * 64;
  const int srow = lane >> 3, sc = lane & 7;

  for (int k0 = 0; k0 < HID; k0 += 64) {
#pragma unroll
    for (int i = 0; i < 2; ++i) {                   // A: 8 segs (64 rows)
      const int seg = w * 2 + i, r = seg * 8 + srow;
      gl_lds16(Aptr + (size_t)(m0 + r) * HID + k0 + swz(sc, srow) * 8, a_lds + seg * 512);
    }
#pragma unroll
    for (int i = 0; i < 4; ++i) {                   // B: 16 segs (128 rows)
      const int seg = w * 4 + i, r = seg * 8 + srow;
      gl_lds16(Bptr + (size_t)(n0 + r) * HID + k0 + swz(sc, srow) * 8, b_lds + seg * 512);
    }
    __syncthreads();
#pragma unroll
    for (int kf = 0; kf < 2; ++kf) {
      bf16x8 af[2], bfr[4];
#pragma unroll
      for (int mt = 0; mt < 2; ++mt)
        af[mt] = *(const bf16x8*)&a_lds[(wm + mt * 16 + l15) * 64 + swz(kf * 4 + quad, l15) * 8];
#pragma unroll
      for (int nt = 0; nt < 4; ++nt)
        bfr[nt] = *(const bf16x8*)&b_lds[(wn + nt * 16 + l15) * 64 + swz(kf * 4 + quad, l15) * 8];
#pragma unroll
      for (int mt = 0; mt < 2; ++mt)
#pragma unroll
        for (int nt = 0; nt < 4; ++nt)
          acc[mt][nt] = __builtin_amdgcn_mfma_f32_16x16x32_bf16(af[mt], bfr[nt], acc[mt][nt], 0, 0, 0);
    }
    __syncthreads();
  }
}

// ---------------- QKV projection: 128x128 tiles, fused RoPE; z=2 writes vT -------------
// q scale folds 1/sqrt(D) AND log2(e) so flash can use raw exp2.
#define QS_LOG2E 0.18033688011112042f   // 0.125 * log2(e)
__global__ __launch_bounds__(256, 2) void qkv_gemm(const u16* __restrict__ xb,
                                                   const u16* __restrict__ Wqb,
                                                   const u16* __restrict__ Wkb,
                                                   const u16* __restrict__ Wvb,
                                                   u16* __restrict__ q, u16* __restrict__ k,
                                                   u16* __restrict__ vT) {
  __shared__ __align__(16) u16 a_lds[128 * 64];
  __shared__ __align__(16) u16 b_lds[128 * 64];
  const int z = blockIdx.z;
  const u16* W = (z == 0) ? Wqb : (z == 1) ? Wkb : Wvb;

  f32x4 acc[4][4];
#pragma unroll
  for (int i = 0; i < 4; ++i)
#pragma unroll
    for (int j = 0; j < 4; ++j) acc[i][j] = (f32x4){0.f, 0.f, 0.f, 0.f};

  const int m0 = blockIdx.y * 128, n0 = blockIdx.x * 128;
  gemm_mainloop(xb, W, a_lds, b_lds, m0, n0, acc);

  const int tid = threadIdx.x, w = tid >> 6, lane = tid & 63;
  const int quad = lane >> 4, l15 = lane & 15;
  const int wm = (w >> 1) * 64, wn = (w & 1) * 64;

  if (z != 2) {   // fused NeoX rope: pairs (d, d+32) = (nt, nt+2) in-thread
    float fr[2];
    fr[0] = __expf(-(float)(l15)      * 0.2878231366242557f);   // 10000^(-d/32)
    fr[1] = __expf(-(float)(16 + l15) * 0.2878231366242557f);
    const float qs = (z == 0) ? QS_LOG2E : 1.f;
#pragma unroll
    for (int mt = 0; mt < 4; ++mt)
#pragma unroll
      for (int r = 0; r < 4; ++r) {
        const int s = (m0 + wm + mt * 16 + quad * 4 + r) & 2047;
#pragma unroll
        for (int p = 0; p < 2; ++p) {
          float c, sn;
          __sincosf((float)s * fr[p], &sn, &c);
          const float t1 = acc[mt][p][r], t2 = acc[mt][p + 2][r];
          acc[mt][p][r]     = (t1 * c - t2 * sn) * qs;
          acc[mt][p + 2][r] = (t2 * c + t1 * sn) * qs;
        }
      }
    u16* dst = (z == 0) ? q : k;
#pragma unroll
    for (int mt = 0; mt < 4; ++mt)
#pragma unroll
      for (int nt = 0; nt < 4; ++nt) {
        const int col = n0 + wn + nt * 16 + l15;       // h*64 + d
        const int h = col >> 6, d = col & 63;
#pragma unroll
        for (int r = 0; r < 4; ++r) {
          const int row = m0 + wm + mt * 16 + quad * 4 + r;   // b*2048 + s
          const int bh  = (row >> 11) * NH + h;
          dst[((size_t)bh * SEQ + (row & 2047)) * HD + d] = f2bf(acc[mt][nt][r]);
        }
      }
  } else {        // V: write transposed vT[bh][d][s] (4 consecutive s -> b64)
#pragma unroll
    for (int mt = 0; mt < 4; ++mt) {
      const int rowbase = m0 + wm + mt * 16 + quad * 4;   // b*2048 + s0, s0%4==0
      const int b = rowbase >> 11, s0 = rowbase & 2047;
#pragma unroll
      for (int nt = 0; nt < 4; ++nt) {
        const int col = n0 + wn + nt * 16 + l15;
        const int h = col >> 6, d = col & 63;
        u16x4 o;
#pragma unroll
        for (int r = 0; r < 4; ++r) o[r] = f2bf(acc[mt][nt][r]);
        *(u16x4*)&vT[((size_t)(b * NH + h) * HD + d) * SEQ + s0] = o;
      }
    }
  }
}

// ---------------- Flash split-K2: 8 waves x 32 q-rows (BM=256), BN=64 ------------------
// 512 threads/block, grid (8,32,2)=512 blocks -> 2 blocks/CU, 16 waves/CU
// (4 waves/SIMD — 2x the latency hiding of r10's 4-wave variant).
__global__ __launch_bounds__(512, 4) void flash(const u16* __restrict__ q,
                                                const u16* __restrict__ k,
                                                const u16* __restrict__ vT,
                                                u16* __restrict__ o0, u16* __restrict__ o1,
                                                float* __restrict__ L0, float* __restrict__ L1) {
  __shared__ __align__(16) u16 ktl[2 * 4096];      // K tiles [key][d], swizzled chunks
  __shared__ __align__(16) u16 vtl[2 * 4096];      // V^T tiles [d][key], swizzled chunks
  __shared__ __align__(16) u16 pl[8 * 16 * 64];    // per-wave P staging, swizzled chunks

  const int tid = threadIdx.x, w = tid >> 6, lane = tid & 63;
  const int quad = lane >> 4, l15 = lane & 15;
  const int srow = lane >> 3, sc = lane & 7;
  const int bh = blockIdx.y;
  const int q0 = blockIdx.x * 256;
  const int z  = blockIdx.z;                       // key half
  u16*   odst = z ? o1 : o0;
  float* Ldst = z ? L1 : L0;

  // Q frags for this wave's 32 q-rows (2 halves); q pre-scaled by 0.125*log2e
  bf16x8 qa[2][2];
#pragma unroll
  for (int qh = 0; qh < 2; ++qh) {
    const u16* qrow = q + ((size_t)bh * SEQ + q0 + w * 32 + qh * 16 + l15) * HD + quad * 8;
    qa[qh][0] = *(const bf16x8*)qrow;
    qa[qh][1] = *(const bf16x8*)(qrow + 32);
  }

  const f32x4 zero4 = (f32x4){0.f, 0.f, 0.f, 0.f};
  f32x4 oacc[2][4];
#pragma unroll
  for (int qh = 0; qh < 2; ++qh)
#pragma unroll
    for (int i = 0; i < 4; ++i) oacc[qh][i] = zero4;
  float L[2] = {0.f, 0.f};             // per-lane row sum for q = qh*16 + l15

  const u16* kbase = k  + (size_t)bh * SEQ * HD + (size_t)z * 1024 * HD;
  const u16* vtb   = vT + (size_t)bh * HD * SEQ + (size_t)z * 1024;

  // prologue: DMA tile 0 into buffer 0 — 64 rows = 8 segs of 8 rows (1 per wave)
  {
    const int seg = w, r = seg * 8 + srow, col = swz(sc, srow) * 8;
    gl_lds16(kbase + (size_t)r * HD + col,  &ktl[seg * 512]);
    gl_lds16(vtb   + (size_t)r * SEQ + col, &vtl[seg * 512]);
  }
  __syncthreads();

  for (int t = 0; t < 16; ++t) {
    const int t0 = t * 64, buf = t & 1;
    if (t < 15) {   // DMA next tile (64 rows) into the other buffer
      const int seg = w, r = seg * 8 + srow, col = swz(sc, srow) * 8;
      gl_lds16(kbase + (size_t)(t0 + 64 + r) * HD + col, &ktl[(buf ^ 1) * 4096 + seg * 512]);
      gl_lds16(vtb   + (size_t)r * SEQ + t0 + 64 + col,  &vtl[(buf ^ 1) * 4096 + seg * 512]);
    }

    // hoisted frags (shared across both q-halves)
    bf16x8 kfr[2][4], bvf[2][4];
#pragma unroll
    for (int kf = 0; kf < 2; ++kf)
#pragma unroll
      for (int nt = 0; nt < 4; ++nt) {
        kfr[kf][nt] = *(const bf16x8*)&ktl[buf * 4096 + (nt * 16 + l15) * 64 + swz(kf * 4 + quad, l15) * 8];
        bvf[kf][nt] = *(const bf16x8*)&vtl[buf * 4096 + (nt * 16 + l15) * 64 + swz(kf * 4 + quad, l15) * 8];
      }

    u16* pw = &pl[w * 16 * 64];
#pragma unroll
    for (int qh = 0; qh < 2; ++qh) {
      // S^T = K Q^T: rows m=key (quad*4+r), cols n=q (l15); C=zero4 (no init movs)
      f32x4 sv[4];
#pragma unroll
      for (int nt = 0; nt < 4; ++nt) {
        sv[nt] = __builtin_amdgcn_mfma_f32_16x16x32_bf16(kfr[0][nt], qa[qh][0], zero4, 0, 0, 0);
        sv[nt] = __builtin_amdgcn_mfma_f32_16x16x32_bf16(kfr[1][nt], qa[qh][1], sv[nt], 0, 0, 0);
      }
      // P^T = exp2(S^T); b64 writes into swizzled chunk layout
#pragma unroll
      for (int nt = 0; nt < 4; ++nt) {
        u16x4 pk;
#pragma unroll
        for (int r = 0; r < 4; ++r) {
          const float pv = EXP2F(sv[nt][r]);
          L[qh] += pv;
          pk[r] = f2bf(pv);
        }
        const int cw = 2 * nt + (quad >> 1);
        *(u16x4*)&pw[l15 * 64 + swz(cw, l15) * 8 + 4 * (quad & 1)] = pk;
      }
      // O += P V  (A = P rows from LDS swizzled chunks, B = V^T frags); same-wave
      // DS ops are in-order, so reusing pw across qh is safe.
#pragma unroll
      for (int kf = 0; kf < 2; ++kf) {
        bf16x8 ap = *(const bf16x8*)&pw[l15 * 64 + swz(kf * 4 + quad, l15) * 8];
#pragma unroll
        for (int dt = 0; dt < 4; ++dt)
          oacc[qh][dt] = __builtin_amdgcn_mfma_f32_16x16x32_bf16(ap, bvf[kf][dt], oacc[qh][dt], 0, 0, 0);
      }
    }
    __syncthreads();   // drains next-tile DMA; releases buffers
  }

  // L reduce across the 4 quads; write raw partials (no normalization here)
#pragma unroll
  for (int qh = 0; qh < 2; ++qh) {
    L[qh] += __shfl_xor(L[qh], 16, 64);
    L[qh] += __shfl_xor(L[qh], 32, 64);
    if (quad == 0) Ldst[(size_t)bh * SEQ + q0 + w * 32 + qh * 16 + l15] = L[qh];
  }

  const int b = bh >> 4, h = bh & 15;
#pragma unroll
  for (int qh = 0; qh < 2; ++qh)
#pragma unroll
    for (int r = 0; r < 4; ++r) {
      const int row = b * SEQ + q0 + w * 32 + qh * 16 + quad * 4 + r;
#pragma unroll
      for (int dt = 0; dt < 4; ++dt)
        odst[(size_t)row * HID + h * HD + dt * 16 + l15] = f2bf(oacc[qh][dt][r]);
    }
}

// ---------------- Combine: attn = (O0 + O1) / (L0 + L1), in place over O0 --------------
__global__ void combine(const u16* __restrict__ o1, const float* __restrict__ L0,
                        const float* __restrict__ L1, u16* __restrict__ attn) {
  const size_t base = ((size_t)blockIdx.x * 256 + threadIdx.x) * 8;
  const int row = (int)(base >> 10);            // [0,4096): b*2048+s
  const int h   = ((int)base & 1023) >> 6;
  const int bh  = (row >> 11) * NH + h;
  const int s   = row & 2047;
  const float inv = 1.f / (L0[(size_t)bh * SEQ + s] + L1[(size_t)bh * SEQ + s]);
  u16x8 a = *(const u16x8*)&attn[base];         // O0 partial (in place)
  u16x8 b = *(const u16x8*)&o1[base];
  u16x8 o;
#pragma unroll
  for (int j = 0; j < 8; ++j) o[j] = f2bf((bf2f(a[j]) + bf2f(b[j])) * inv);
  *(u16x8*)&attn[base] = o;
}

// ---------------- Output projection: 64x128 tiles (512 blocks) -------------------------
__global__ __launch_bounds__(256, 4) void out_gemm(const u16* __restrict__ attn,
                                                   const u16* __restrict__ Wob,
                                                   float* __restrict__ out) {
  __shared__ __align__(16) u16 a_lds[64 * 64];
  __shared__ __align__(16) u16 b_lds[128 * 64];
  f32x4 acc[2][4];
#pragma unroll
  for (int i = 0; i < 2; ++i)
#pragma unroll
    for (int j = 0; j < 4; ++j) acc[i][j] = (f32x4){0.f, 0.f, 0.f, 0.f};

  const int m0 = blockIdx.y * 64, n0 = blockIdx.x * 128;
  gemm64_mainloop(attn, Wob, a_lds, b_lds, m0, n0, acc);

  const int tid = threadIdx.x, w = tid >> 6, lane = tid & 63;
  const int quad = lane >> 4, l15 = lane & 15;
  const int wm = (w >> 1) * 32, wn = (w & 1) * 64;
#pragma unroll
  for (int mt = 0; mt < 2; ++mt)
#pragma unroll
    for (int nt = 0; nt < 4; ++nt) {
      const int col = n0 + wn + nt * 16 + l15;
#pragma unroll
      for (int r = 0; r < 4; ++r) {
        const int row = m0 + wm + mt * 16 + quad * 4 + r;
        out[(size_t)row * HID + col] = acc[mt][nt][r];
      }
    }
}

// ---------------- launch ---------------------------------------------------------------
extern "C" void kernel_launch(void* const* d_in, const int* in_sizes, int n_in,
                              void* d_out, int out_size, void* d_ws, size_t ws_size,
                              hipStream_t stream) {
  const float* x  = (const float*)d_in[0];
  const float* Wq = (const float*)d_in[1];
  const float* Wk = (const float*)d_in[2];
  const float* Wv = (const float*)d_in[3];
  const float* Wo = (const float*)d_in[4];
  float* out = (float*)d_out;

  // d_out as scratch (all dead before out_gemm's writes):
  char* os = (char*)d_out;
  u16* Wqb = (u16*)(os);                     // 2MB   (dead after qkv)
  u16* Wkb = (u16*)(os + (2u << 20));        // 2MB
  u16* Wvb = (u16*)(os + (4u << 20));        // 2MB
  u16* xb  = (u16*)(os + (6u << 20));        // 8MB
  u16*   o1 = (u16*)(os);                    // 8MB partial O (z=1), post-qkv
  float* L0 = (float*)(os + (8u << 20));     // 256KB
  float* L1 = (float*)(os + (8u << 20) + (256u << 10));

  char* ws = (char*)d_ws;                    // 32MB
  u16* q    = (u16*)(ws);                    // 8MB; dead after flash
  u16* Wob  = (u16*)(ws);                    // 2MB over dead q
  u16* k    = (u16*)(ws + (8u << 20));       // 8MB
  u16* vT   = (u16*)(ws + (16u << 20));      // 8MB  [bh][d][s]
  u16* attn = (u16*)(ws + (24u << 20));      // 8MB; partial O (z=0), then combined

  cvt_pre<<<dim3(2048, 4), 256, 0, stream>>>(x, Wq, Wk, Wv, xb, Wqb, Wkb, Wvb);
  qkv_gemm<<<dim3(8, 32, 3), 256, 0, stream>>>(xb, Wqb, Wkb, Wvb, q, k, vT);
  flash<<<dim3(8, 32, 2), 512, 0, stream>>>(q, k, vT, attn, o1, L0, L1);
  cvt_wo<<<dim3(512), 256, 0, stream>>>(Wo, Wob);
  combine<<<dim3(2048), 256, 0, stream>>>(o1, L0, L1, attn);
  out_gemm<<<dim3(8, 64), 256, 0, stream>>>(attn, Wob, out);
}

// Round 2
// 180.301 us; speedup vs baseline: 1.0056x; 1.0056x over previous
//
#include <hip/hip_runtime.h>

// Attention_11940009083141 — MI355X, round 12.
// B=2, S=2048, HID=1024, NH=16, HD=64. FP32 in/out; bf16 MFMA internally.
//
// r11 post-mortem: doubling waves/SIMD (2->4) moved occupancy 17.8->35.4 but
// MfmaUtil/VALUBusy/time were EXACTLY flat. With r9 (VALU diet flat) this
// proves flash is lockstep-structure-bound: one __syncthreads per tile drains
// vmcnt(0) and couples all waves to the slowest DMA every 64-key tile.
//
// Round-12:
//  * flash: counted-vmcnt 3-buffer pipeline (T4). Issue tile t+2 while
//    computing t; raw s_barrier with asm vmcnt(2) — prefetch pair stays in
//    flight ACROSS the barrier; never drain to 0 in the main loop.
//  * split-K2 dropped (occupancy proven non-binding): grid (8,32), 32 tiles
//    per block, 1/L normalization fused into the flash epilogue (shfl
//    broadcast). combine kernel DELETED — saves 32MB of partial traffic, one
//    launch, and halves Q fetch. o1/L0/L1 scratch gone.
//
// ws (32MB): q[0,8M) k[8,16M) vT[16,24M) attn[24,32M); Wob over dead q.
// d_out scratch: pre-qkv Wqb@0 Wkb@2M Wvb@4M xb@6M (all dead before out_gemm).

typedef unsigned short u16;
typedef __bf16 bf16x8 __attribute__((ext_vector_type(8)));
typedef float  f32x4  __attribute__((ext_vector_type(4)));
typedef u16    u16x8  __attribute__((ext_vector_type(8)));
typedef u16    u16x4  __attribute__((ext_vector_type(4)));

#define HID 1024
#define SEQ 2048
#define NH  16
#define HD  64

#if __has_builtin(__builtin_amdgcn_exp2f)
#define EXP2F(x) __builtin_amdgcn_exp2f(x)
#else
#define EXP2F(x) exp2f(x)
#endif

__device__ __forceinline__ float bf2f(u16 u) { return __uint_as_float(((unsigned)u) << 16); }
// f32 -> bf16 RNE via native cast
__device__ __forceinline__ u16 f2bf(float f) {
  union { __bf16 h; u16 u; } c;
  c.h = (__bf16)f;
  return c.u;
}
__device__ __forceinline__ void gl_lds16(const void* g, void* l) {
  __builtin_amdgcn_global_load_lds((const __attribute__((address_space(1))) void*)g,
                                   (__attribute__((address_space(3))) void*)l, 16, 0, 0);
}
__device__ __forceinline__ void stage_f32(const float* __restrict__ src, u16* dst) {
  float4 f0 = *(const float4*)src;
  float4 f1 = *(const float4*)(src + 4);
  u16x8 o;
  o[0] = f2bf(f0.x); o[1] = f2bf(f0.y); o[2] = f2bf(f0.z); o[3] = f2bf(f0.w);
  o[4] = f2bf(f1.x); o[5] = f2bf(f1.y); o[6] = f2bf(f1.z); o[7] = f2bf(f1.w);
  *(u16x8*)dst = o;
}
// XOR chunk swizzle: logical 8-u16 chunk c of row r lives at physical chunk c^(r&7)
__device__ __forceinline__ int swz(int c, int r) { return c ^ (r & 7); }

// ---------------- fp32 -> bf16 converts ------------------------------------------------
__global__ void cvt_pre(const float* __restrict__ x,  const float* __restrict__ Wq,
                        const float* __restrict__ Wk, const float* __restrict__ Wv,
                        u16* __restrict__ xb, u16* __restrict__ Wqb,
                        u16* __restrict__ Wkb, u16* __restrict__ Wvb) {
  const int z = blockIdx.y;
  const float* src; u16* dst; int nchunk;
  switch (z) {
    case 0:  src = x;  dst = xb;  nchunk = 524288; break;
    case 1:  src = Wq; dst = Wqb; nchunk = 131072; break;
    case 2:  src = Wk; dst = Wkb; nchunk = 131072; break;
    default: src = Wv; dst = Wvb; nchunk = 131072; break;
  }
  const int i = blockIdx.x * 256 + threadIdx.x;
  if (i >= nchunk) return;
  stage_f32(src + (size_t)i * 8, dst + (size_t)i * 8);
}
__global__ void cvt_wo(const float* __restrict__ Wo, u16* __restrict__ Wob) {
  const int i = blockIdx.x * 256 + threadIdx.x;   // 131072 chunks
  stage_f32(Wo + (size_t)i * 8, Wob + (size_t)i * 8);
}

// ---------------- NT GEMM mainloop: 128x128 tile, BK=64, K=1024, two-sided DMA --------
__device__ __forceinline__ void gemm_mainloop(const u16* __restrict__ Aptr,
                                              const u16* __restrict__ Bptr,
                                              u16* a_lds, u16* b_lds,
                                              int m0, int n0, f32x4 (&acc)[4][4]) {
  const int tid  = threadIdx.x;
  const int w    = tid >> 6;
  const int lane = tid & 63;
  const int quad = lane >> 4, l15 = lane & 15;
  const int wm = (w >> 1) * 64, wn = (w & 1) * 64;
  const int srow = lane >> 3, sc = lane & 7;        // DMA roles: 8 rows x 8 chunks

  for (int k0 = 0; k0 < HID; k0 += 64) {
#pragma unroll
    for (int i = 0; i < 4; ++i) {
      const int seg = w * 4 + i;                    // 16 segs of 8 rows per 128x64 tile
      const int r   = seg * 8 + srow;
      const int col = k0 + swz(sc, srow) * 8;       // swizzled source column
      gl_lds16(Aptr + (size_t)(m0 + r) * HID + col, a_lds + seg * 512);
      gl_lds16(Bptr + (size_t)(n0 + r) * HID + col, b_lds + seg * 512);
    }
    __syncthreads();
#pragma unroll
    for (int kf = 0; kf < 2; ++kf) {
      bf16x8 af[4], bfr[4];
#pragma unroll
      for (int mt = 0; mt < 4; ++mt)
        af[mt] = *(const bf16x8*)&a_lds[(wm + mt * 16 + l15) * 64 + swz(kf * 4 + quad, l15) * 8];
#pragma unroll
      for (int nt = 0; nt < 4; ++nt)
        bfr[nt] = *(const bf16x8*)&b_lds[(wn + nt * 16 + l15) * 64 + swz(kf * 4 + quad, l15) * 8];
#pragma unroll
      for (int mt = 0; mt < 4; ++mt)
#pragma unroll
        for (int nt = 0; nt < 4; ++nt)
          acc[mt][nt] = __builtin_amdgcn_mfma_f32_16x16x32_bf16(af[mt], bfr[nt], acc[mt][nt], 0, 0, 0);
    }
    __syncthreads();
  }
}

// ---------------- NT GEMM mainloop: 64x128 tile (out_gemm) -----------------------------
__device__ __forceinline__ void gemm64_mainloop(const u16* __restrict__ Aptr,
                                                const u16* __restrict__ Bptr,
                                                u16* a_lds, u16* b_lds,
                                                int m0, int n0, f32x4 (&acc)[2][4]) {
  const int tid  = threadIdx.x;
  const int w    = tid >> 6;
  const int lane = tid & 63;
  const int quad = lane >> 4, l15 = lane & 15;
  const int wm = (w >> 1) * 32, wn = (w & 1) * 64;
  const int srow = lane >> 3, sc = lane & 7;

  for (int k0 = 0; k0 < HID; k0 += 64) {
#pragma unroll
    for (int i = 0; i < 2; ++i) {                   // A: 8 segs (64 rows)
      const int seg = w * 2 + i, r = seg * 8 + srow;
      gl_lds16(Aptr + (size_t)(m0 + r) * HID + k0 + swz(sc, srow) * 8, a_lds + seg * 512);
    }
#pragma unroll
    for (int i = 0; i < 4; ++i) {                   // B: 16 segs (128 rows)
      const int seg = w * 4 + i, r = seg * 8 + srow;
      gl_lds16(Bptr + (size_t)(n0 + r) * HID + k0 + swz(sc, srow) * 8, b_lds + seg * 512);
    }
    __syncthreads();
#pragma unroll
    for (int kf = 0; kf < 2; ++kf) {
      bf16x8 af[2], bfr[4];
#pragma unroll
      for (int mt = 0; mt < 2; ++mt)
        af[mt] = *(const bf16x8*)&a_lds[(wm + mt * 16 + l15) * 64 + swz(kf * 4 + quad, l15) * 8];
#pragma unroll
      for (int nt = 0; nt < 4; ++nt)
        bfr[nt] = *(const bf16x8*)&b_lds[(wn + nt * 16 + l15) * 64 + swz(kf * 4 + quad, l15) * 8];
#pragma unroll
      for (int mt = 0; mt < 2; ++mt)
#pragma unroll
        for (int nt = 0; nt < 4; ++nt)
          acc[mt][nt] = __builtin_amdgcn_mfma_f32_16x16x32_bf16(af[mt], bfr[nt], acc[mt][nt], 0, 0, 0);
    }
    __syncthreads();
  }
}

// ---------------- QKV projection: 128x128 tiles, fused RoPE; z=2 writes vT -------------
// q scale folds 1/sqrt(D) AND log2(e) so flash can use raw exp2.
#define QS_LOG2E 0.18033688011112042f   // 0.125 * log2(e)
__global__ __launch_bounds__(256, 2) void qkv_gemm(const u16* __restrict__ xb,
                                                   const u16* __restrict__ Wqb,
                                                   const u16* __restrict__ Wkb,
                                                   const u16* __restrict__ Wvb,
                                                   u16* __restrict__ q, u16* __restrict__ k,
                                                   u16* __restrict__ vT) {
  __shared__ __align__(16) u16 a_lds[128 * 64];
  __shared__ __align__(16) u16 b_lds[128 * 64];
  const int z = blockIdx.z;
  const u16* W = (z == 0) ? Wqb : (z == 1) ? Wkb : Wvb;

  f32x4 acc[4][4];
#pragma unroll
  for (int i = 0; i < 4; ++i)
#pragma unroll
    for (int j = 0; j < 4; ++j) acc[i][j] = (f32x4){0.f, 0.f, 0.f, 0.f};

  const int m0 = blockIdx.y * 128, n0 = blockIdx.x * 128;
  gemm_mainloop(xb, W, a_lds, b_lds, m0, n0, acc);

  const int tid = threadIdx.x, w = tid >> 6, lane = tid & 63;
  const int quad = lane >> 4, l15 = lane & 15;
  const int wm = (w >> 1) * 64, wn = (w & 1) * 64;

  if (z != 2) {   // fused NeoX rope: pairs (d, d+32) = (nt, nt+2) in-thread
    float fr[2];
    fr[0] = __expf(-(float)(l15)      * 0.2878231366242557f);   // 10000^(-d/32)
    fr[1] = __expf(-(float)(16 + l15) * 0.2878231366242557f);
    const float qs = (z == 0) ? QS_LOG2E : 1.f;
#pragma unroll
    for (int mt = 0; mt < 4; ++mt)
#pragma unroll
      for (int r = 0; r < 4; ++r) {
        const int s = (m0 + wm + mt * 16 + quad * 4 + r) & 2047;
#pragma unroll
        for (int p = 0; p < 2; ++p) {
          float c, sn;
          __sincosf((float)s * fr[p], &sn, &c);
          const float t1 = acc[mt][p][r], t2 = acc[mt][p + 2][r];
          acc[mt][p][r]     = (t1 * c - t2 * sn) * qs;
          acc[mt][p + 2][r] = (t2 * c + t1 * sn) * qs;
        }
      }
    u16* dst = (z == 0) ? q : k;
#pragma unroll
    for (int mt = 0; mt < 4; ++mt)
#pragma unroll
      for (int nt = 0; nt < 4; ++nt) {
        const int col = n0 + wn + nt * 16 + l15;       // h*64 + d
        const int h = col >> 6, d = col & 63;
#pragma unroll
        for (int r = 0; r < 4; ++r) {
          const int row = m0 + wm + mt * 16 + quad * 4 + r;   // b*2048 + s
          const int bh  = (row >> 11) * NH + h;
          dst[((size_t)bh * SEQ + (row & 2047)) * HD + d] = f2bf(acc[mt][nt][r]);
        }
      }
  } else {        // V: write transposed vT[bh][d][s] (4 consecutive s -> b64)
#pragma unroll
    for (int mt = 0; mt < 4; ++mt) {
      const int rowbase = m0 + wm + mt * 16 + quad * 4;   // b*2048 + s0, s0%4==0
      const int b = rowbase >> 11, s0 = rowbase & 2047;
#pragma unroll
      for (int nt = 0; nt < 4; ++nt) {
        const int col = n0 + wn + nt * 16 + l15;
        const int h = col >> 6, d = col & 63;
        u16x4 o;
#pragma unroll
        for (int r = 0; r < 4; ++r) o[r] = f2bf(acc[mt][nt][r]);
        *(u16x4*)&vT[((size_t)(b * NH + h) * HD + d) * SEQ + s0] = o;
      }
    }
  }
}

// ---------------- Flash, full-key: 8 waves x 32 q-rows (BM=256), 32 tiles of 64 keys ---
// 3-buffer counted-vmcnt pipeline: issue tile t+2 while computing t; barrier
// waits vmcnt(2) so the deepest prefetch pair stays in flight across it.
// Grid (8,32) = 256 blocks (1/CU — occupancy proven non-binding in r11).
// Epilogue normalizes by 1/L (shfl broadcast) and writes final bf16 attn.
__global__ __launch_bounds__(512, 2) void flash(const u16* __restrict__ q,
                                                const u16* __restrict__ k,
                                                const u16* __restrict__ vT,
                                                u16* __restrict__ attn) {
  __shared__ __align__(16) u16 ktl[3 * 4096];      // K tiles [key][d], swizzled chunks
  __shared__ __align__(16) u16 vtl[3 * 4096];      // V^T tiles [d][key], swizzled chunks
  __shared__ __align__(16) u16 pl[8 * 16 * 64];    // per-wave P staging, swizzled chunks

  const int tid = threadIdx.x, w = tid >> 6, lane = tid & 63;
  const int quad = lane >> 4, l15 = lane & 15;
  const int srow = lane >> 3, sc = lane & 7;
  const int bh = blockIdx.y;
  const int q0 = blockIdx.x * 256;

  const u16* kbase = k  + (size_t)bh * SEQ * HD;
  const u16* vtb   = vT + (size_t)bh * HD * SEQ;

  // Q frags FIRST (so prologue vmcnt(2) also covers their completion).
  bf16x8 qa[2][2];
#pragma unroll
  for (int qh = 0; qh < 2; ++qh) {
    const u16* qrow = q + ((size_t)bh * SEQ + q0 + w * 32 + qh * 16 + l15) * HD + quad * 8;
    qa[qh][0] = *(const bf16x8*)qrow;
    qa[qh][1] = *(const bf16x8*)(qrow + 32);
  }

  // DMA roles: wave w stages seg w (8 rows) of each 64-row tile.
  const int r8 = w * 8 + srow;
  const int colsw = swz(sc, srow) * 8;
#define ISSUE(T, B) do {                                                              \
    gl_lds16(kbase + (size_t)((T) * 64 + r8) * HD + colsw, &ktl[(B) * 4096 + w * 512]); \
    gl_lds16(vtb + (size_t)r8 * SEQ + (T) * 64 + colsw,    &vtl[(B) * 4096 + w * 512]); \
  } while (0)

  ISSUE(0, 0);
  ISSUE(1, 1);
  asm volatile("s_waitcnt vmcnt(2)" ::: "memory");   // Q + tile0 done; tile1 in flight
  __builtin_amdgcn_s_barrier();
  __builtin_amdgcn_sched_barrier(0);

  const f32x4 zero4 = (f32x4){0.f, 0.f, 0.f, 0.f};
  f32x4 oacc[2][4];
#pragma unroll
  for (int qh = 0; qh < 2; ++qh)
#pragma unroll
    for (int i = 0; i < 4; ++i) oacc[qh][i] = zero4;
  float L[2] = {0.f, 0.f};             // per-lane row sum for q = qh*16 + l15

  auto compute = [&](int cb) {
    const u16* kc = &ktl[cb * 4096];
    const u16* vc = &vtl[cb * 4096];
    bf16x8 kfr[2][4], bvf[2][4];
#pragma unroll
    for (int kf = 0; kf < 2; ++kf)
#pragma unroll
      for (int nt = 0; nt < 4; ++nt) {
        kfr[kf][nt] = *(const bf16x8*)&kc[(nt * 16 + l15) * 64 + swz(kf * 4 + quad, l15) * 8];
        bvf[kf][nt] = *(const bf16x8*)&vc[(nt * 16 + l15) * 64 + swz(kf * 4 + quad, l15) * 8];
      }
    u16* pw = &pl[w * 16 * 64];
#pragma unroll
    for (int qh = 0; qh < 2; ++qh) {
      // S^T = K Q^T: rows m=key (quad*4+r), cols n=q (l15); C=zero4 (no init movs)
      f32x4 sv[4];
#pragma unroll
      for (int nt = 0; nt < 4; ++nt) {
        sv[nt] = __builtin_amdgcn_mfma_f32_16x16x32_bf16(kfr[0][nt], qa[qh][0], zero4, 0, 0, 0);
        sv[nt] = __builtin_amdgcn_mfma_f32_16x16x32_bf16(kfr[1][nt], qa[qh][1], sv[nt], 0, 0, 0);
      }
      // P^T = exp2(S^T); b64 writes into swizzled chunk layout
#pragma unroll
      for (int nt = 0; nt < 4; ++nt) {
        u16x4 pk;
#pragma unroll
        for (int r = 0; r < 4; ++r) {
          const float pv = EXP2F(sv[nt][r]);
          L[qh] += pv;
          pk[r] = f2bf(pv);
        }
        const int cw = 2 * nt + (quad >> 1);
        *(u16x4*)&pw[l15 * 64 + swz(cw, l15) * 8 + 4 * (quad & 1)] = pk;
      }
      // O += P V  (A = P rows from LDS swizzled chunks, B = V^T frags); same-wave
      // DS ops are in-order, so reusing pw across qh is safe.
#pragma unroll
      for (int kf = 0; kf < 2; ++kf) {
        bf16x8 ap = *(const bf16x8*)&pw[l15 * 64 + swz(kf * 4 + quad, l15) * 8];
#pragma unroll
        for (int dt = 0; dt < 4; ++dt)
          oacc[qh][dt] = __builtin_amdgcn_mfma_f32_16x16x32_bf16(ap, bvf[kf][dt], oacc[qh][dt], 0, 0, 0);
      }
    }
  };

  // main loop: tiles 0..29 with depth-2 prefetch; counted vmcnt(2) at barrier
  int cur = 0, nxt = 2;
  for (int t = 0; t < 30; ++t) {
    ISSUE(t + 2, nxt);
    __builtin_amdgcn_sched_barrier(0);   // keep issue ahead of frag reads
    compute(cur);
    asm volatile("s_waitcnt vmcnt(2)" ::: "memory");  // tile t+1 landed; t+2 in flight
    __builtin_amdgcn_s_barrier();
    __builtin_amdgcn_sched_barrier(0);
    cur = (cur == 2) ? 0 : cur + 1;
    nxt = (nxt == 2) ? 0 : nxt + 1;
  }
  // t = 30 (cur == 0): no more issues; drain last pair for tile 31
  compute(0);
  asm volatile("s_waitcnt vmcnt(0)" ::: "memory");
  __builtin_amdgcn_s_barrier();
  __builtin_amdgcn_sched_barrier(0);
  // t = 31 (cur == 1)
  compute(1);
#undef ISSUE

  // epilogue: full L reduce (all lanes), broadcast per output row, normalize, store
  const int b = bh >> 4, h = bh & 15;
#pragma unroll
  for (int qh = 0; qh < 2; ++qh) {
    float Lf = L[qh];
    Lf += __shfl_xor(Lf, 16, 64);
    Lf += __shfl_xor(Lf, 32, 64);        // all lanes: total sum for q = qh*16 + l15
    float inv[4];
#pragma unroll
    for (int r = 0; r < 4; ++r) inv[r] = 1.f / __shfl(Lf, quad * 4 + r, 64);
#pragma unroll
    for (int r = 0; r < 4; ++r) {
      const int row = b * SEQ + q0 + w * 32 + qh * 16 + quad * 4 + r;
#pragma unroll
      for (int dt = 0; dt < 4; ++dt)
        attn[(size_t)row * HID + h * HD + dt * 16 + l15] = f2bf(oacc[qh][dt][r] * inv[r]);
    }
  }
}

// ---------------- Output projection: 64x128 tiles (512 blocks) -------------------------
__global__ __launch_bounds__(256, 4) void out_gemm(const u16* __restrict__ attn,
                                                   const u16* __restrict__ Wob,
                                                   float* __restrict__ out) {
  __shared__ __align__(16) u16 a_lds[64 * 64];
  __shared__ __align__(16) u16 b_lds[128 * 64];
  f32x4 acc[2][4];
#pragma unroll
  for (int i = 0; i < 2; ++i)
#pragma unroll
    for (int j = 0; j < 4; ++j) acc[i][j] = (f32x4){0.f, 0.f, 0.f, 0.f};

  const int m0 = blockIdx.y * 64, n0 = blockIdx.x * 128;
  gemm64_mainloop(attn, Wob, a_lds, b_lds, m0, n0, acc);

  const int tid = threadIdx.x, w = tid >> 6, lane = tid & 63;
  const int quad = lane >> 4, l15 = lane & 15;
  const int wm = (w >> 1) * 32, wn = (w & 1) * 64;
#pragma unroll
  for (int mt = 0; mt < 2; ++mt)
#pragma unroll
    for (int nt = 0; nt < 4; ++nt) {
      const int col = n0 + wn + nt * 16 + l15;
#pragma unroll
      for (int r = 0; r < 4; ++r) {
        const int row = m0 + wm + mt * 16 + quad * 4 + r;
        out[(size_t)row * HID + col] = acc[mt][nt][r];
      }
    }
}

// ---------------- launch ---------------------------------------------------------------
extern "C" void kernel_launch(void* const* d_in, const int* in_sizes, int n_in,
                              void* d_out, int out_size, void* d_ws, size_t ws_size,
                              hipStream_t stream) {
  const float* x  = (const float*)d_in[0];
  const float* Wq = (const float*)d_in[1];
  const float* Wk = (const float*)d_in[2];
  const float* Wv = (const float*)d_in[3];
  const float* Wo = (const float*)d_in[4];
  float* out = (float*)d_out;

  // d_out as scratch (all dead before out_gemm's writes):
  char* os = (char*)d_out;
  u16* Wqb = (u16*)(os);                     // 2MB   (dead after qkv)
  u16* Wkb = (u16*)(os + (2u << 20));        // 2MB
  u16* Wvb = (u16*)(os + (4u << 20));        // 2MB
  u16* xb  = (u16*)(os + (6u << 20));        // 8MB

  char* ws = (char*)d_ws;                    // 32MB
  u16* q    = (u16*)(ws);                    // 8MB; dead after flash
  u16* Wob  = (u16*)(ws);                    // 2MB over dead q
  u16* k    = (u16*)(ws + (8u << 20));       // 8MB
  u16* vT   = (u16*)(ws + (16u << 20));      // 8MB  [bh][d][s]
  u16* attn = (u16*)(ws + (24u << 20));      // 8MB; final normalized O

  cvt_pre<<<dim3(2048, 4), 256, 0, stream>>>(x, Wq, Wk, Wv, xb, Wqb, Wkb, Wvb);
  qkv_gemm<<<dim3(8, 32, 3), 256, 0, stream>>>(xb, Wqb, Wkb, Wvb, q, k, vT);
  flash<<<dim3(8, 32), 512, 0, stream>>>(q, k, vT, attn);
  cvt_wo<<<dim3(512), 256, 0, stream>>>(Wo, Wob);
  out_gemm<<<dim3(8, 64), 256, 0, stream>>>(attn, Wob, out);
}

// Round 3
// 174.066 us; speedup vs baseline: 1.0416x; 1.0358x over previous
//
#include <hip/hip_runtime.h>

// Attention_11940009083141 — MI355X, round 13.
// B=2, S=2048, HID=1024, NH=16, HD=64. FP32 in/out; bf16 MFMA internally.
//
// r12 post-mortem: counted-vmcnt was confounded by grid halving (1 block/CU
// lost cross-block interleave; flash 51->54.8). WRITE 26->8MB yet total flat
// -> split-K2 overhead == its benefit. FETCH 69.7MB vs 24 ideal: grid had
// XCD = q-chunk (id%8), so every XCD touched all 32 bh's K/V.
//
// Round-13:
//  * flash: BM=128, 4 waves x 32 q-rows, grid (bh=32, q=16) = 512 blocks =
//    2 blocks/CU; bh -> XCD partition (4 bh/XCD, K+V 2MB L2-fit).
//  * in-register P (T12): cvt_pk_bf16 + permlane32/16_swap rebuild the PV
//    A-fragment in VGPRs — P LDS round-trip deleted (pl buffer gone, LDS
//    32KB, -64KB/tile/CU LDS traffic, no in-order lgkm chain).
//  * setprio(1) around MFMA cluster (T5); r11-proven 2-buffer sync loop.
//  * qkv/out_gemm grids transposed (m-chunk -> XCD): W/xb panels L2-resident.
//
// ws (32MB): q[0,8M) k[8,16M) vT[16,24M) attn[24,32M); Wob over dead q.
// d_out scratch: pre-qkv Wqb@0 Wkb@2M Wvb@4M xb@6M (all dead before out_gemm).

typedef unsigned short u16;
typedef unsigned int   u32;
typedef __bf16 bf16x8 __attribute__((ext_vector_type(8)));
typedef float  f32x4  __attribute__((ext_vector_type(4)));
typedef u16    u16x8  __attribute__((ext_vector_type(8)));
typedef u16    u16x4  __attribute__((ext_vector_type(4)));
typedef u32    u32x4  __attribute__((ext_vector_type(4)));

#define HID 1024
#define SEQ 2048
#define NH  16
#define HD  64

#if __has_builtin(__builtin_amdgcn_exp2f)
#define EXP2F(x) __builtin_amdgcn_exp2f(x)
#else
#define EXP2F(x) exp2f(x)
#endif

__device__ __forceinline__ float bf2f(u16 u) { return __uint_as_float(((unsigned)u) << 16); }
// f32 -> bf16 RNE via native cast
__device__ __forceinline__ u16 f2bf(float f) {
  union { __bf16 h; u16 u; } c;
  c.h = (__bf16)f;
  return c.u;
}
__device__ __forceinline__ void gl_lds16(const void* g, void* l) {
  __builtin_amdgcn_global_load_lds((const __attribute__((address_space(1))) void*)g,
                                   (__attribute__((address_space(3))) void*)l, 16, 0, 0);
}
__device__ __forceinline__ void stage_f32(const float* __restrict__ src, u16* dst) {
  float4 f0 = *(const float4*)src;
  float4 f1 = *(const float4*)(src + 4);
  u16x8 o;
  o[0] = f2bf(f0.x); o[1] = f2bf(f0.y); o[2] = f2bf(f0.z); o[3] = f2bf(f0.w);
  o[4] = f2bf(f1.x); o[5] = f2bf(f1.y); o[6] = f2bf(f1.z); o[7] = f2bf(f1.w);
  *(u16x8*)dst = o;
}
// XOR chunk swizzle: logical 8-u16 chunk c of row r lives at physical chunk c^(r&7)
__device__ __forceinline__ int swz(int c, int r) { return c ^ (r & 7); }

// ---------------- fp32 -> bf16 converts ------------------------------------------------
__global__ void cvt_pre(const float* __restrict__ x,  const float* __restrict__ Wq,
                        const float* __restrict__ Wk, const float* __restrict__ Wv,
                        u16* __restrict__ xb, u16* __restrict__ Wqb,
                        u16* __restrict__ Wkb, u16* __restrict__ Wvb) {
  const int z = blockIdx.y;
  const float* src; u16* dst; int nchunk;
  switch (z) {
    case 0:  src = x;  dst = xb;  nchunk = 524288; break;
    case 1:  src = Wq; dst = Wqb; nchunk = 131072; break;
    case 2:  src = Wk; dst = Wkb; nchunk = 131072; break;
    default: src = Wv; dst = Wvb; nchunk = 131072; break;
  }
  const int i = blockIdx.x * 256 + threadIdx.x;
  if (i >= nchunk) return;
  stage_f32(src + (size_t)i * 8, dst + (size_t)i * 8);
}
__global__ void cvt_wo(const float* __restrict__ Wo, u16* __restrict__ Wob) {
  const int i = blockIdx.x * 256 + threadIdx.x;   // 131072 chunks
  stage_f32(Wo + (size_t)i * 8, Wob + (size_t)i * 8);
}

// ---------------- NT GEMM mainloop: 128x128 tile, BK=64, K=1024, two-sided DMA --------
__device__ __forceinline__ void gemm_mainloop(const u16* __restrict__ Aptr,
                                              const u16* __restrict__ Bptr,
                                              u16* a_lds, u16* b_lds,
                                              int m0, int n0, f32x4 (&acc)[4][4]) {
  const int tid  = threadIdx.x;
  const int w    = tid >> 6;
  const int lane = tid & 63;
  const int quad = lane >> 4, l15 = lane & 15;
  const int wm = (w >> 1) * 64, wn = (w & 1) * 64;
  const int srow = lane >> 3, sc = lane & 7;        // DMA roles: 8 rows x 8 chunks

  for (int k0 = 0; k0 < HID; k0 += 64) {
#pragma unroll
    for (int i = 0; i < 4; ++i) {
      const int seg = w * 4 + i;                    // 16 segs of 8 rows per 128x64 tile
      const int r   = seg * 8 + srow;
      const int col = k0 + swz(sc, srow) * 8;       // swizzled source column
      gl_lds16(Aptr + (size_t)(m0 + r) * HID + col, a_lds + seg * 512);
      gl_lds16(Bptr + (size_t)(n0 + r) * HID + col, b_lds + seg * 512);
    }
    __syncthreads();
#pragma unroll
    for (int kf = 0; kf < 2; ++kf) {
      bf16x8 af[4], bfr[4];
#pragma unroll
      for (int mt = 0; mt < 4; ++mt)
        af[mt] = *(const bf16x8*)&a_lds[(wm + mt * 16 + l15) * 64 + swz(kf * 4 + quad, l15) * 8];
#pragma unroll
      for (int nt = 0; nt < 4; ++nt)
        bfr[nt] = *(const bf16x8*)&b_lds[(wn + nt * 16 + l15) * 64 + swz(kf * 4 + quad, l15) * 8];
#pragma unroll
      for (int mt = 0; mt < 4; ++mt)
#pragma unroll
        for (int nt = 0; nt < 4; ++nt)
          acc[mt][nt] = __builtin_amdgcn_mfma_f32_16x16x32_bf16(af[mt], bfr[nt], acc[mt][nt], 0, 0, 0);
    }
    __syncthreads();
  }
}

// ---------------- NT GEMM mainloop: 64x128 tile (out_gemm) -----------------------------
__device__ __forceinline__ void gemm64_mainloop(const u16* __restrict__ Aptr,
                                                const u16* __restrict__ Bptr,
                                                u16* a_lds, u16* b_lds,
                                                int m0, int n0, f32x4 (&acc)[2][4]) {
  const int tid  = threadIdx.x;
  const int w    = tid >> 6;
  const int lane = tid & 63;
  const int quad = lane >> 4, l15 = lane & 15;
  const int wm = (w >> 1) * 32, wn = (w & 1) * 64;
  const int srow = lane >> 3, sc = lane & 7;

  for (int k0 = 0; k0 < HID; k0 += 64) {
#pragma unroll
    for (int i = 0; i < 2; ++i) {                   // A: 8 segs (64 rows)
      const int seg = w * 2 + i, r = seg * 8 + srow;
      gl_lds16(Aptr + (size_t)(m0 + r) * HID + k0 + swz(sc, srow) * 8, a_lds + seg * 512);
    }
#pragma unroll
    for (int i = 0; i < 4; ++i) {                   // B: 16 segs (128 rows)
      const int seg = w * 4 + i, r = seg * 8 + srow;
      gl_lds16(Bptr + (size_t)(n0 + r) * HID + k0 + swz(sc, srow) * 8, b_lds + seg * 512);
    }
    __syncthreads();
#pragma unroll
    for (int kf = 0; kf < 2; ++kf) {
      bf16x8 af[2], bfr[4];
#pragma unroll
      for (int mt = 0; mt < 2; ++mt)
        af[mt] = *(const bf16x8*)&a_lds[(wm + mt * 16 + l15) * 64 + swz(kf * 4 + quad, l15) * 8];
#pragma unroll
      for (int nt = 0; nt < 4; ++nt)
        bfr[nt] = *(const bf16x8*)&b_lds[(wn + nt * 16 + l15) * 64 + swz(kf * 4 + quad, l15) * 8];
#pragma unroll
      for (int mt = 0; mt < 2; ++mt)
#pragma unroll
        for (int nt = 0; nt < 4; ++nt)
          acc[mt][nt] = __builtin_amdgcn_mfma_f32_16x16x32_bf16(af[mt], bfr[nt], acc[mt][nt], 0, 0, 0);
    }
    __syncthreads();
  }
}

// ---------------- QKV projection: 128x128 tiles, fused RoPE; z=2 writes vT -------------
// Grid (32, 8, 3): x = m-chunk -> XCD partition (xb panels L2-resident per XCD).
// q scale folds 1/sqrt(D) AND log2(e) so flash can use raw exp2.
#define QS_LOG2E 0.18033688011112042f   // 0.125 * log2(e)
__global__ __launch_bounds__(256, 2) void qkv_gemm(const u16* __restrict__ xb,
                                                   const u16* __restrict__ Wqb,
                                                   const u16* __restrict__ Wkb,
                                                   const u16* __restrict__ Wvb,
                                                   u16* __restrict__ q, u16* __restrict__ k,
                                                   u16* __restrict__ vT) {
  __shared__ __align__(16) u16 a_lds[128 * 64];
  __shared__ __align__(16) u16 b_lds[128 * 64];
  const int z = blockIdx.z;
  const u16* W = (z == 0) ? Wqb : (z == 1) ? Wkb : Wvb;

  f32x4 acc[4][4];
#pragma unroll
  for (int i = 0; i < 4; ++i)
#pragma unroll
    for (int j = 0; j < 4; ++j) acc[i][j] = (f32x4){0.f, 0.f, 0.f, 0.f};

  const int m0 = blockIdx.x * 128, n0 = blockIdx.y * 128;
  gemm_mainloop(xb, W, a_lds, b_lds, m0, n0, acc);

  const int tid = threadIdx.x, w = tid >> 6, lane = tid & 63;
  const int quad = lane >> 4, l15 = lane & 15;
  const int wm = (w >> 1) * 64, wn = (w & 1) * 64;

  if (z != 2) {   // fused NeoX rope: pairs (d, d+32) = (nt, nt+2) in-thread
    float fr[2];
    fr[0] = __expf(-(float)(l15)      * 0.2878231366242557f);   // 10000^(-d/32)
    fr[1] = __expf(-(float)(16 + l15) * 0.2878231366242557f);
    const float qs = (z == 0) ? QS_LOG2E : 1.f;
#pragma unroll
    for (int mt = 0; mt < 4; ++mt)
#pragma unroll
      for (int r = 0; r < 4; ++r) {
        const int s = (m0 + wm + mt * 16 + quad * 4 + r) & 2047;
#pragma unroll
        for (int p = 0; p < 2; ++p) {
          float c, sn;
          __sincosf((float)s * fr[p], &sn, &c);
          const float t1 = acc[mt][p][r], t2 = acc[mt][p + 2][r];
          acc[mt][p][r]     = (t1 * c - t2 * sn) * qs;
          acc[mt][p + 2][r] = (t2 * c + t1 * sn) * qs;
        }
      }
    u16* dst = (z == 0) ? q : k;
#pragma unroll
    for (int mt = 0; mt < 4; ++mt)
#pragma unroll
      for (int nt = 0; nt < 4; ++nt) {
        const int col = n0 + wn + nt * 16 + l15;       // h*64 + d
        const int h = col >> 6, d = col & 63;
#pragma unroll
        for (int r = 0; r < 4; ++r) {
          const int row = m0 + wm + mt * 16 + quad * 4 + r;   // b*2048 + s
          const int bh  = (row >> 11) * NH + h;
          dst[((size_t)bh * SEQ + (row & 2047)) * HD + d] = f2bf(acc[mt][nt][r]);
        }
      }
  } else {        // V: write transposed vT[bh][d][s] (4 consecutive s -> b64)
#pragma unroll
    for (int mt = 0; mt < 4; ++mt) {
      const int rowbase = m0 + wm + mt * 16 + quad * 4;   // b*2048 + s0, s0%4==0
      const int b = rowbase >> 11, s0 = rowbase & 2047;
#pragma unroll
      for (int nt = 0; nt < 4; ++nt) {
        const int col = n0 + wn + nt * 16 + l15;
        const int h = col >> 6, d = col & 63;
        u16x4 o;
#pragma unroll
        for (int r = 0; r < 4; ++r) o[r] = f2bf(acc[mt][nt][r]);
        *(u16x4*)&vT[((size_t)(b * NH + h) * HD + d) * SEQ + s0] = o;
      }
    }
  }
}

// ---------------- Flash, full-key: 4 waves x 32 q-rows (BM=128), 32 tiles of 64 keys ---
// Grid (32, 16): x = bh -> XCD partition (4 bh/XCD, K+V 2MB L2-resident).
// 512 blocks = 2 blocks/CU. In-register P: cvt_pk_bf16_f32 packs, then
// permlane32_swap + permlane16_swap rebuild the PV A-fragment without LDS.
__global__ __launch_bounds__(256, 2) void flash(const u16* __restrict__ q,
                                                const u16* __restrict__ k,
                                                const u16* __restrict__ vT,
                                                u16* __restrict__ attn) {
  __shared__ __align__(16) u16 ktl[2 * 4096];      // K tiles [key][d], swizzled chunks
  __shared__ __align__(16) u16 vtl[2 * 4096];      // V^T tiles [d][key], swizzled chunks

  const int tid = threadIdx.x, w = tid >> 6, lane = tid & 63;
  const int quad = lane >> 4, l15 = lane & 15;
  const int srow = lane >> 3, sc = lane & 7;
  const int bh = blockIdx.x;                       // id%8 = bh%8 -> XCD partition
  const int q0 = blockIdx.y * 128;

  const u16* kbase = k  + (size_t)bh * SEQ * HD;
  const u16* vtb   = vT + (size_t)bh * HD * SEQ;

  // Q frags for this wave's 32 q-rows; q pre-scaled by 0.125*log2e
  bf16x8 qa[2][2];
#pragma unroll
  for (int qh = 0; qh < 2; ++qh) {
    const u16* qrow = q + ((size_t)bh * SEQ + q0 + w * 32 + qh * 16 + l15) * HD + quad * 8;
    qa[qh][0] = *(const bf16x8*)qrow;
    qa[qh][1] = *(const bf16x8*)(qrow + 32);
  }

  const int colsw = swz(sc, srow) * 8;
  // DMA roles: wave w stages segs {2w, 2w+1} (8 rows each) of K and V tiles.
#define ISSUE(T, B) do {                                                                  \
    _Pragma("unroll")                                                                     \
    for (int i = 0; i < 2; ++i) {                                                         \
      const int seg = w * 2 + i, r = seg * 8 + srow;                                      \
      gl_lds16(kbase + (size_t)((T) * 64 + r) * HD + colsw, &ktl[(B) * 4096 + seg * 512]); \
      gl_lds16(vtb + (size_t)r * SEQ + (T) * 64 + colsw,    &vtl[(B) * 4096 + seg * 512]); \
    } } while (0)

  const f32x4 zero4 = (f32x4){0.f, 0.f, 0.f, 0.f};
  f32x4 oacc[2][4];
#pragma unroll
  for (int qh = 0; qh < 2; ++qh)
#pragma unroll
    for (int i = 0; i < 4; ++i) oacc[qh][i] = zero4;
  float L[2] = {0.f, 0.f};             // per-lane row sum for q = qh*16 + l15

  ISSUE(0, 0);
  __syncthreads();

  for (int t = 0; t < 32; ++t) {
    const int buf = t & 1;
    if (t < 31) ISSUE(t + 1, buf ^ 1);

    const u16* kc = &ktl[buf * 4096];
    const u16* vc = &vtl[buf * 4096];
    bf16x8 kfr[2][4], bvf[2][4];
#pragma unroll
    for (int kf = 0; kf < 2; ++kf)
#pragma unroll
      for (int nt = 0; nt < 4; ++nt) {
        kfr[kf][nt] = *(const bf16x8*)&kc[(nt * 16 + l15) * 64 + swz(kf * 4 + quad, l15) * 8];
        bvf[kf][nt] = *(const bf16x8*)&vc[(nt * 16 + l15) * 64 + swz(kf * 4 + quad, l15) * 8];
      }

    __builtin_amdgcn_s_setprio(1);
#pragma unroll
    for (int qh = 0; qh < 2; ++qh) {
      // S^T = K Q^T: rows m=key (quad*4+r), cols n=q (l15); C=zero4 (no init movs)
      f32x4 sv[4];
#pragma unroll
      for (int nt = 0; nt < 4; ++nt) {
        sv[nt] = __builtin_amdgcn_mfma_f32_16x16x32_bf16(kfr[0][nt], qa[qh][0], zero4, 0, 0, 0);
        sv[nt] = __builtin_amdgcn_mfma_f32_16x16x32_bf16(kfr[1][nt], qa[qh][1], sv[nt], 0, 0, 0);
      }
      // P^T = exp2(S^T), packed to bf16 pairs in-register.
      // pd[nt][e] dword = bf16(keys nt*16+quad*4+2e, +2e+1) at q-col l15.
      u32 pd[4][2];
#pragma unroll
      for (int nt = 0; nt < 4; ++nt)
#pragma unroll
        for (int e = 0; e < 2; ++e) {
          const float p0 = EXP2F(sv[nt][2 * e]);
          const float p1 = EXP2F(sv[nt][2 * e + 1]);
          L[qh] += p0 + p1;
          asm("v_cvt_pk_bf16_f32 %0, %1, %2" : "=v"(pd[nt][e]) : "v"(p0), "v"(p1));
        }
      // Rebuild PV A-frags in-register (T12). After 32swap(a,b):
      //   a = {a.lo32lanes, b.lo32lanes}, b = {a.hi, b.hi};
      // after 16swap(a,b): a = {A.r0,B.r0,A.r2,B.r2}, b = {A.r1,B.r1,A.r3,B.r3}.
      // Result per lane (quad,l15): ap[kf] = P[q=l15][keys kf*32+quad*8 .. +7].
#pragma unroll
      for (int kf = 0; kf < 2; ++kf) {
        u32 a0 = pd[2 * kf][0], b0 = pd[2 * kf + 1][0];
        u32 a1 = pd[2 * kf][1], b1 = pd[2 * kf + 1][1];
        asm("v_permlane32_swap_b32 %0, %1" : "+v"(a0), "+v"(b0));
        asm("v_permlane32_swap_b32 %0, %1" : "+v"(a1), "+v"(b1));
        asm("v_permlane16_swap_b32 %0, %1" : "+v"(a0), "+v"(b0));
        asm("v_permlane16_swap_b32 %0, %1" : "+v"(a1), "+v"(b1));
        const u32x4 apw = (u32x4){a0, a1, b0, b1};
        const bf16x8 ap = __builtin_bit_cast(bf16x8, apw);
#pragma unroll
        for (int dt = 0; dt < 4; ++dt)
          oacc[qh][dt] = __builtin_amdgcn_mfma_f32_16x16x32_bf16(ap, bvf[kf][dt], oacc[qh][dt], 0, 0, 0);
      }
    }
    __builtin_amdgcn_s_setprio(0);
    __syncthreads();   // drains next-tile DMA; releases buffers
  }
#undef ISSUE

  // epilogue: full L reduce (all lanes), broadcast per output row, normalize, store
  const int b = bh >> 4, h = bh & 15;
#pragma unroll
  for (int qh = 0; qh < 2; ++qh) {
    float Lf = L[qh];
    Lf += __shfl_xor(Lf, 16, 64);
    Lf += __shfl_xor(Lf, 32, 64);        // all lanes: total sum for q = qh*16 + l15
    float inv[4];
#pragma unroll
    for (int r = 0; r < 4; ++r) inv[r] = 1.f / __shfl(Lf, quad * 4 + r, 64);
#pragma unroll
    for (int r = 0; r < 4; ++r) {
      const int row = b * SEQ + q0 + w * 32 + qh * 16 + quad * 4 + r;
#pragma unroll
      for (int dt = 0; dt < 4; ++dt)
        attn[(size_t)row * HID + h * HD + dt * 16 + l15] = f2bf(oacc[qh][dt][r] * inv[r]);
    }
  }
}

// ---------------- Output projection: 64x128 tiles; grid (64,8), m-chunk -> XCD --------
__global__ __launch_bounds__(256, 4) void out_gemm(const u16* __restrict__ attn,
                                                   const u16* __restrict__ Wob,
                                                   float* __restrict__ out) {
  __shared__ __align__(16) u16 a_lds[64 * 64];
  __shared__ __align__(16) u16 b_lds[128 * 64];
  f32x4 acc[2][4];
#pragma unroll
  for (int i = 0; i < 2; ++i)
#pragma unroll
    for (int j = 0; j < 4; ++j) acc[i][j] = (f32x4){0.f, 0.f, 0.f, 0.f};

  const int m0 = blockIdx.x * 64, n0 = blockIdx.y * 128;
  gemm64_mainloop(attn, Wob, a_lds, b_lds, m0, n0, acc);

  const int tid = threadIdx.x, w = tid >> 6, lane = tid & 63;
  const int quad = lane >> 4, l15 = lane & 15;
  const int wm = (w >> 1) * 32, wn = (w & 1) * 64;
#pragma unroll
  for (int mt = 0; mt < 2; ++mt)
#pragma unroll
    for (int nt = 0; nt < 4; ++nt) {
      const int col = n0 + wn + nt * 16 + l15;
#pragma unroll
      for (int r = 0; r < 4; ++r) {
        const int row = m0 + wm + mt * 16 + quad * 4 + r;
        out[(size_t)row * HID + col] = acc[mt][nt][r];
      }
    }
}

// ---------------- launch ---------------------------------------------------------------
extern "C" void kernel_launch(void* const* d_in, const int* in_sizes, int n_in,
                              void* d_out, int out_size, void* d_ws, size_t ws_size,
                              hipStream_t stream) {
  const float* x  = (const float*)d_in[0];
  const float* Wq = (const float*)d_in[1];
  const float* Wk = (const float*)d_in[2];
  const float* Wv = (const float*)d_in[3];
  const float* Wo = (const float*)d_in[4];
  float* out = (float*)d_out;

  // d_out as scratch (all dead before out_gemm's writes):
  char* os = (char*)d_out;
  u16* Wqb = (u16*)(os);                     // 2MB   (dead after qkv)
  u16* Wkb = (u16*)(os + (2u << 20));        // 2MB
  u16* Wvb = (u16*)(os + (4u << 20));        // 2MB
  u16* xb  = (u16*)(os + (6u << 20));        // 8MB

  char* ws = (char*)d_ws;                    // 32MB
  u16* q    = (u16*)(ws);                    // 8MB; dead after flash
  u16* Wob  = (u16*)(ws);                    // 2MB over dead q
  u16* k    = (u16*)(ws + (8u << 20));       // 8MB
  u16* vT   = (u16*)(ws + (16u << 20));      // 8MB  [bh][d][s]
  u16* attn = (u16*)(ws + (24u << 20));      // 8MB; final normalized O

  cvt_pre<<<dim3(2048, 4), 256, 0, stream>>>(x, Wq, Wk, Wv, xb, Wqb, Wkb, Wvb);
  qkv_gemm<<<dim3(32, 8, 3), 256, 0, stream>>>(xb, Wqb, Wkb, Wvb, q, k, vT);
  flash<<<dim3(32, 16), 256, 0, stream>>>(q, k, vT, attn);
  cvt_wo<<<dim3(512), 256, 0, stream>>>(Wo, Wob);
  out_gemm<<<dim3(64, 8), 256, 0, stream>>>(attn, Wob, out);
}